// Round 7
// baseline (158.969 us; speedup 1.0000x reference)
//
#include <hip/hip_runtime.h>
#include <stdint.h>
#include <stddef.h>

// Problem constants
#define HOUT 64
#define WOUT 64
#define CIN  32
#define COUT 16
#define SLOC 4096          // HOUT*WOUT
#define KTOT 288           // CIN*9
#define HPAD 66            // 64 + 2 pad
#define WPAD 148           // dwords per n-row of LDS W tile (9*16=144 + 4 pad)
// Padded-X pixel block = BATCH*CIN bf16 = 2048 ushorts = 4096 bytes

typedef __attribute__((ext_vector_type(8))) short  short8;   // 8 bf16 (4 VGPRs)
typedef __attribute__((ext_vector_type(4))) float  floatx4;  // MFMA acc / float4
typedef __attribute__((ext_vector_type(2))) float  floatx2;

// fp32 -> bf16 round-to-nearest-even (bit pattern)
static __device__ __forceinline__ unsigned short f2bf(float f) {
    union { float f; unsigned int u; } v; v.f = f;
    unsigned int u = v.u;
    unsigned int r = (u + 0x7FFFu + ((u >> 16) & 1u)) >> 16;
    return (unsigned short)r;
}

// packed fp32x2 -> bf16x2 (RTNE), single instruction (no builtin on gfx950)
static __device__ __forceinline__ unsigned int cvt_pk_bf16(float lo, float hi) {
    unsigned int r;
    asm("v_cvt_pk_bf16_f32 %0, %1, %2" : "=v"(r) : "v"(lo), "v"(hi));
    return r;
}

// ---------------------------------------------------------------------------
// Prep kernel: border-zero + X transpose. 2048 blocks x 256 threads.
// (unchanged from R6 -- controlled experiment on varconv only)
// ---------------------------------------------------------------------------
__global__ __launch_bounds__(256) void prep_kernel(const float* __restrict__ X,
                                                   unsigned short* __restrict__ xt) {
    const int id  = blockIdx.x;
    const int tid = threadIdx.x;

    // ---- border zero: 260 x 4KB pixel blocks, handled by blocks 0..259 ----
    if (id < 260) {
        int h1, w1;
        if (id < 66)       { h1 = 0;  w1 = id; }
        else if (id < 132) { h1 = 65; w1 = id - 66; }
        else { int r = id - 132; h1 = (r >> 1) + 1; w1 = (r & 1) ? 65 : 0; }
        ((uint4*)(xt + (size_t)(h1 * HPAD + w1) * 2048))[tid] = uint4{0u, 0u, 0u, 0u};
    }

    // ---- transpose X[b][c][h][w] fp32 -> xt[(h+1)][(w+1)][b][c] bf16 ----
    const int w   = tid >> 2;        // 0..63
    const int cg8 = (tid & 3) * 8;   // channel group base
#pragma unroll
    for (int u = 0; u < 2; ++u) {
        const int unit = id * 2 + u;            // 0..4095
        const int h = unit >> 6, b = unit & 63;
        const float* xb = X + (((size_t)b * CIN + cg8) * HOUT + h) * WOUT + w;
        unsigned short v[8];
#pragma unroll
        for (int j = 0; j < 8; ++j)
            v[j] = f2bf(xb[(size_t)j * HOUT * WOUT]);
        uint4 pack;
        pack.x = (unsigned)v[0] | ((unsigned)v[1] << 16);
        pack.y = (unsigned)v[2] | ((unsigned)v[3] << 16);
        pack.z = (unsigned)v[4] | ((unsigned)v[5] << 16);
        pack.w = (unsigned)v[6] | ((unsigned)v[7] << 16);
        *(uint4*)(xt + (size_t)((h + 1) * HPAD + (w + 1)) * 2048 + b * CIN + cg8) = pack;
    }
}

// ---------------------------------------------------------------------------
// Main kernel (R7): R6 structure (block = 2 sites x 64 batches, 256 thr,
// grid 2048, one barrier, batched-ILP loads, conflict-free LDS W layout)
// with phase 3 slimmed (R6 post-mortem: phase 3 -- f2bf VALU chains +
// 16 shfl_xor colsum + cs LDS -- sits between the vmcnt drain and the
// barrier on every lockstep block):
//   - colsum via ones-MFMA: accc += mfma(ones, bf[t], accc) reuses the
//     B-fragments already read; row r of accc == colsum_k(bf16 W)[n].
//     Deletes cacc adds, all 16 shfl_xor, the cs buffer + combine.
//   - v_cvt_pk_bf16_f32: 1 instr per packed dword (was ~10 VALU).
// ---------------------------------------------------------------------------
__global__ __launch_bounds__(256, 4) void varconv_kernel(const unsigned short* __restrict__ xt,
                                                         const float* __restrict__ Wg,
                                                         const float* __restrict__ bias,
                                                         float* __restrict__ out) {
    __shared__ __align__(16) unsigned int wru[2][16 * WPAD];  // 2 sites, 18.5 KB

    const int id   = blockIdx.x;                   // 0..2047
    const int sg   = (id & 7) * 256 + (id >> 3);   // site-group, XCD-contiguous
    const int s0   = sg * 2;
    const int y    = s0 >> 6;
    const int x0   = s0 & 63;                      // even; x0+3 <= 65 within pad
    const int tid  = threadIdx.x;
    const int lane = tid & 63;
    const int wv   = tid >> 6;                     // batch quarter
    const int q    = lane >> 4;                    // channel octet
    const int n    = lane & 15;                    // c_out (B/D); batch-in-quarter (A)
    const int B0   = wv * 16;

    const float bias0 = bias[s0];
    const float bias1 = bias[s0 + 1];

    // ---- phase 1: issue all staging loads (both sites, 36 KB contiguous) ----
    const uint4* wsrc = (const uint4*)(Wg + (size_t)s0 * (KTOT * COUT));
    uint4 fA[5], fB[5];
#pragma unroll
    for (int it = 0; it < 5; ++it) {
        const int tau  = tid + it * 256;           // 0..1279; 1152 real tasks
        const int tt   = tau < 1152 ? tau : 1151;  // dup-load tail (masked later)
        const int site = tt >= 576;
        const int t2   = tt - 576 * site;
        const int ng = t2 & 3, cp = (t2 >> 2) & 15, t = t2 >> 6;
        const int kA = 18 * cp + t;                // row c=2cp ; +9 -> c=2cp+1
        fA[it] = wsrc[site * 1152 + kA * 4 + ng];
        fB[it] = wsrc[site * 1152 + (kA + 9) * 4 + ng];
    }

    // ---- phase 2: issue all A-fragment loads (12 shared across both sites) ----
    const unsigned short* abase = xt + (size_t)(B0 + n) * CIN + q * 8;
    short8 af[3][4];
#pragma unroll
    for (int cy = 0; cy < 3; ++cy)
#pragma unroll
        for (int cx = 0; cx < 4; ++cx)
            af[cy][cx] = *(const short8*)(abase + (size_t)((y + cy) * HPAD + (x0 + cx)) * 2048);

    // ---- phase 3: convert + conflict-free LDS scatter (no colsum) ----
    // LDS dword L(n,t,cp) = n*WPAD + t*16 + cp packs bf16(W[2cp*9+t][n]) |
    // bf16(W[(2cp+1)*9+t][n])<<16. Per wave-instr t is constant -> 16 cp's x
    // ng-parity = 2 lanes/bank (free).
#pragma unroll
    for (int it = 0; it < 5; ++it) {
        const int tau = tid + it * 256;
        if (tau < 1152) {
            const int site = tau >= 576;           // LDS base index (not a reg array)
            const int t2   = tau - 576 * site;
            const int ng = t2 & 3, cp = (t2 >> 2) & 15, t = t2 >> 6;
            union { uint4 u; float f[4]; } a, b;
            a.u = fA[it]; b.u = fB[it];
            unsigned int* wb = &wru[site][t * 16 + cp];
#pragma unroll
            for (int m = 0; m < 4; ++m)
                wb[(4 * ng + m) * WPAD] = cvt_pk_bf16(a.f[m], b.f[m]);
        }
    }

    __syncthreads();

    // ---- phase 4: B-frags from LDS + MFMAs on resident A-regs ----
    // Read ds_read_b128 at n*WPAD + t*16 + 4q: 8 dwords/bank (b128 minimum).
    // accc (A == 1.0) accumulates colsum_k(bf16 W)[n] in every row -- the
    // bias term -- reusing the same B-fragment reads.
    const short one = (short)0x3F80;               // bf16 1.0
    const short8 ones = {one, one, one, one, one, one, one, one};
    floatx4 acc0  = {0.f, 0.f, 0.f, 0.f};
    floatx4 acc1  = {0.f, 0.f, 0.f, 0.f};
    floatx4 accc0 = {0.f, 0.f, 0.f, 0.f};
    floatx4 accc1 = {0.f, 0.f, 0.f, 0.f};
    const unsigned int* w0 = &wru[0][n * WPAD + 4 * q];
    const unsigned int* w1 = &wru[1][n * WPAD + 4 * q];
#pragma unroll
    for (int t = 0; t < 9; ++t) {
        const int cy = t / 3, cx = t % 3;
        const short8 b0 = *(const short8*)(w0 + t * 16);
        acc0  = __builtin_amdgcn_mfma_f32_16x16x32_bf16(af[cy][cx], b0, acc0, 0, 0, 0);
        accc0 = __builtin_amdgcn_mfma_f32_16x16x32_bf16(ones, b0, accc0, 0, 0, 0);
        const short8 b1 = *(const short8*)(w1 + t * 16);
        acc1  = __builtin_amdgcn_mfma_f32_16x16x32_bf16(af[cy][cx + 1], b1, acc1, 0, 0, 0);
        accc1 = __builtin_amdgcn_mfma_f32_16x16x32_bf16(ones, b1, accc1, 0, 0, 0);
    }

    // ---- epilogue: lane (q,n) holds rows b=B0+4q+r, col c=n, 2 consec s ----
#pragma unroll
    for (int r = 0; r < 4; ++r) {
        const int b = B0 + 4 * q + r;
        float* dst = out + ((size_t)(b * COUT + n)) * SLOC + s0;
        *(floatx2*)dst = floatx2{acc0[r] + bias0 * accc0[r],
                                 acc1[r] + bias1 * accc1[r]};
    }
}

extern "C" void kernel_launch(void* const* d_in, const int* in_sizes, int n_in,
                              void* d_out, int out_size, void* d_ws, size_t ws_size,
                              hipStream_t stream) {
    const float* X    = (const float*)d_in[0];   // [64][32][64][64] fp32
    const float* Wg   = (const float*)d_in[1];   // [4096][288][16] fp32
    const float* bias = (const float*)d_in[2];   // [4096] fp32
    float* out = (float*)d_out;                  // [64][16][4096] fp32

    // Workspace: xt only: 66*66*64*32*2 = 17,842,176 B
    unsigned short* xt = (unsigned short*)d_ws;

    prep_kernel<<<2048, 256, 0, stream>>>(X, xt);
    varconv_kernel<<<2048, 256, 0, stream>>>(xt, Wg, bias, out);
}

// Round 8
// 156.935 us; speedup vs baseline: 1.0130x; 1.0130x over previous
//
#include <hip/hip_runtime.h>
#include <stdint.h>
#include <stddef.h>

// Problem constants
#define HOUT 64
#define WOUT 64
#define CIN  32
#define COUT 16
#define SLOC 4096          // HOUT*WOUT
#define KTOT 288           // CIN*9
#define HPAD 66            // 64 + 2 pad
#define WPAD 148           // dwords per n-row of LDS W tile (9*16=144 + 4 pad)
// Padded-X pixel block = BATCH*CIN bf16 = 2048 ushorts = 4096 bytes

typedef __attribute__((ext_vector_type(8))) short  short8;   // 8 bf16 (4 VGPRs)
typedef __attribute__((ext_vector_type(4))) float  floatx4;  // MFMA acc / float4

// fp32 -> bf16 round-to-nearest-even (bit pattern). Scalar form: R7 showed
// the inline-asm v_cvt_pk_bf16_f32 regressed (compiler schedules this better).
static __device__ __forceinline__ unsigned short f2bf(float f) {
    union { float f; unsigned int u; } v; v.f = f;
    unsigned int u = v.u;
    unsigned int r = (u + 0x7FFFu + ((u >> 16) & 1u)) >> 16;
    return (unsigned short)r;
}

// ---------------------------------------------------------------------------
// Prep kernel: border-zero + X transpose. 2048 blocks x 256 threads.
// R8: unit assignment remapped for XCD affinity -- block p (on XCD p&7 by
// round-robin dispatch) handles rows h in [8k, 8k+8), exactly the rows the
// varconv blocks of XCD k will read -> xt A-loads become local-L2 hits.
// ---------------------------------------------------------------------------
__global__ __launch_bounds__(256) void prep_kernel(const float* __restrict__ X,
                                                   unsigned short* __restrict__ xt) {
    const int id  = blockIdx.x;
    const int tid = threadIdx.x;

    // ---- border zero: 260 x 4KB pixel blocks, handled by blocks 0..259 ----
    if (id < 260) {
        int h1, w1;
        if (id < 66)       { h1 = 0;  w1 = id; }
        else if (id < 132) { h1 = 65; w1 = id - 66; }
        else { int r = id - 132; h1 = (r >> 1) + 1; w1 = (r & 1) ? 65 : 0; }
        ((uint4*)(xt + (size_t)(h1 * HPAD + w1) * 2048))[tid] = uint4{0u, 0u, 0u, 0u};
    }

    // ---- transpose X[b][c][h][w] fp32 -> xt[(h+1)][(w+1)][b][c] bf16 ----
    const int w   = tid >> 2;        // 0..63
    const int cg8 = (tid & 3) * 8;   // channel group base
    const int k   = id & 7;          // XCD (dispatch round-robin)
    const int j   = id >> 3;         // 0..255
#pragma unroll
    for (int u = 0; u < 2; ++u) {
        const int unit = k * 512 + j * 2 + u;   // XCD k -> h in [8k, 8k+8)
        const int h = unit >> 6, b = unit & 63;
        const float* xb = X + (((size_t)b * CIN + cg8) * HOUT + h) * WOUT + w;
        unsigned short v[8];
#pragma unroll
        for (int jj = 0; jj < 8; ++jj)
            v[jj] = f2bf(xb[(size_t)jj * HOUT * WOUT]);
        uint4 pack;
        pack.x = (unsigned)v[0] | ((unsigned)v[1] << 16);
        pack.y = (unsigned)v[2] | ((unsigned)v[3] << 16);
        pack.z = (unsigned)v[4] | ((unsigned)v[5] << 16);
        pack.w = (unsigned)v[6] | ((unsigned)v[7] << 16);
        *(uint4*)(xt + (size_t)((h + 1) * HPAD + (w + 1)) * 2048 + b * CIN + cg8) = pack;
    }
}

// ---------------------------------------------------------------------------
// Main kernel (R8): block = 4 consecutive sites x 64 batches, 256 threads,
// grid 1024 (4 blocks/CU). vs R6: half the blocks (half the fixed per-block
// costs), xt re-read 98->74 MB, epilogue stores widen 8B->16B. Staging in
// TWO 10-load rounds (40-VGPR window) so the 18 A-loads (72 VGPR) + one
// round fit the 128-VGPR cap; round-1 scatter drains only round-1 W loads.
// Colsum via ones-MFMA (kept from R7); f2bf scalar (cvt_pk asm reverted).
//
// LDS W layout per site (conflict-free, from R4): dword L(n,t,cp) =
// n*WPAD + t*16 + cp packs bf16(W[2cp*9+t][n]) | bf16(W[(2cp+1)*9+t][n])<<16.
// Stage tasks are 64-aligned in (site,t) -> write = 2 lanes/bank (free).
// Read ds_read_b128 at n*WPAD + t*16 + 4q -> 8 dwords/bank (b128 minimum).
// ---------------------------------------------------------------------------
__global__ __launch_bounds__(256, 4) void varconv_kernel(const unsigned short* __restrict__ xt,
                                                         const float* __restrict__ Wg,
                                                         const float* __restrict__ bias,
                                                         float* __restrict__ out) {
    __shared__ __align__(16) unsigned int wru[4][16 * WPAD];  // 4 sites, 37 KB

    const int id   = blockIdx.x;                   // 0..1023
    const int sg   = (id & 7) * 128 + (id >> 3);   // site-group, XCD-contiguous
    const int s0   = sg * 4;                       // 4 consecutive sites
    const int y    = s0 >> 6;                      // = sg >> 4
    const int x0   = s0 & 63;                      // multiple of 4; x0+5 <= 65
    const int tid  = threadIdx.x;
    const int lane = tid & 63;
    const int wv   = tid >> 6;                     // batch quarter
    const int q    = lane >> 4;                    // channel octet
    const int n    = lane & 15;                    // c_out (B/D); batch-in-quarter (A)
    const int B0   = wv * 16;

    const uint4* wsrc = (const uint4*)(Wg + (size_t)s0 * (KTOT * COUT));

    // ---- issue staging round 1 (sites 0,1) ----
    uint4 fA[5], fB[5];
#define WISSUE(ROUND)                                                          \
    _Pragma("unroll")                                                          \
    for (int it = 0; it < 5; ++it) {                                           \
        const int tau  = tid + it * 256;           /* 0..1279; 1152 real */    \
        const int tt   = tau < 1152 ? tau : 1151;  /* dup-load tail */         \
        const int site = (tt >= 576) + 2 * (ROUND);                            \
        const int t2   = tt - 576 * (tt >= 576);                               \
        const int ng = t2 & 3, cp = (t2 >> 2) & 15, t = t2 >> 6;               \
        const int kA = 18 * cp + t;                /* row c=2cp; +9 -> 2cp+1 */\
        fA[it] = wsrc[site * 1152 + kA * 4 + ng];                              \
        fB[it] = wsrc[site * 1152 + (kA + 9) * 4 + ng];                        \
    }

#define WSCATTER(ROUND)                                                        \
    _Pragma("unroll")                                                          \
    for (int it = 0; it < 5; ++it) {                                           \
        const int tau = tid + it * 256;                                        \
        if (tau < 1152) {                                                      \
            const int site = (tau >= 576) + 2 * (ROUND);                       \
            const int t2   = tau - 576 * (tau >= 576);                         \
            const int ng = t2 & 3, cp = (t2 >> 2) & 15, t = t2 >> 6;           \
            union { uint4 u; float f[4]; } a, b;                               \
            a.u = fA[it]; b.u = fB[it];                                        \
            unsigned int* wb = &wru[site][t * 16 + cp];                        \
            _Pragma("unroll")                                                  \
            for (int m = 0; m < 4; ++m)                                        \
                wb[(4 * ng + m) * WPAD] =                                      \
                    (unsigned)f2bf(a.f[m]) | ((unsigned)f2bf(b.f[m]) << 16);   \
        }                                                                      \
    }

    WISSUE(0)

    // ---- issue all A-fragment loads (18, shared across the 4 sites) ----
    const unsigned short* abase = xt + (size_t)(B0 + n) * CIN + q * 8;
    short8 af[3][6];
#pragma unroll
    for (int cy = 0; cy < 3; ++cy)
#pragma unroll
        for (int cx = 0; cx < 6; ++cx)
            af[cy][cx] = *(const short8*)(abase + (size_t)((y + cy) * HPAD + (x0 + cx)) * 2048);

    // ---- scatter round 1 (waits round-1 W only; A + nothing else needed) ----
    WSCATTER(0)

    // ---- issue + scatter round 2 (sites 2,3) ----
    WISSUE(1)
    WSCATTER(1)
#undef WISSUE
#undef WSCATTER

    __syncthreads();

    // ---- phase 4: B-frags from LDS + MFMAs on resident A-regs ----
    // accc (A == 1.0) accumulates colsum_k(bf16 W)[n] -> bias term, reusing
    // the same B-fragment reads (no shfl/LDS reduction needed).
    const short one = (short)0x3F80;               // bf16 1.0
    const short8 ones = {one, one, one, one, one, one, one, one};
    floatx4 acc0  = {0.f, 0.f, 0.f, 0.f}, accc0 = {0.f, 0.f, 0.f, 0.f};
    floatx4 acc1  = {0.f, 0.f, 0.f, 0.f}, accc1 = {0.f, 0.f, 0.f, 0.f};
    floatx4 acc2  = {0.f, 0.f, 0.f, 0.f}, accc2 = {0.f, 0.f, 0.f, 0.f};
    floatx4 acc3  = {0.f, 0.f, 0.f, 0.f}, accc3 = {0.f, 0.f, 0.f, 0.f};
    const unsigned int* w0 = &wru[0][n * WPAD + 4 * q];
    const unsigned int* w1 = &wru[1][n * WPAD + 4 * q];
    const unsigned int* w2 = &wru[2][n * WPAD + 4 * q];
    const unsigned int* w3 = &wru[3][n * WPAD + 4 * q];
#pragma unroll
    for (int t = 0; t < 9; ++t) {
        const int cy = t / 3, cx = t % 3;
        const short8 b0 = *(const short8*)(w0 + t * 16);
        acc0  = __builtin_amdgcn_mfma_f32_16x16x32_bf16(af[cy][cx],     b0, acc0,  0, 0, 0);
        accc0 = __builtin_amdgcn_mfma_f32_16x16x32_bf16(ones,           b0, accc0, 0, 0, 0);
        const short8 b1 = *(const short8*)(w1 + t * 16);
        acc1  = __builtin_amdgcn_mfma_f32_16x16x32_bf16(af[cy][cx + 1], b1, acc1,  0, 0, 0);
        accc1 = __builtin_amdgcn_mfma_f32_16x16x32_bf16(ones,           b1, accc1, 0, 0, 0);
        const short8 b2 = *(const short8*)(w2 + t * 16);
        acc2  = __builtin_amdgcn_mfma_f32_16x16x32_bf16(af[cy][cx + 2], b2, acc2,  0, 0, 0);
        accc2 = __builtin_amdgcn_mfma_f32_16x16x32_bf16(ones,           b2, accc2, 0, 0, 0);
        const short8 b3 = *(const short8*)(w3 + t * 16);
        acc3  = __builtin_amdgcn_mfma_f32_16x16x32_bf16(af[cy][cx + 3], b3, acc3,  0, 0, 0);
        accc3 = __builtin_amdgcn_mfma_f32_16x16x32_bf16(ones,           b3, accc3, 0, 0, 0);
    }
    const float bias0 = bias[s0];
    const float bias1 = bias[s0 + 1];
    const float bias2 = bias[s0 + 2];
    const float bias3 = bias[s0 + 3];

    // ---- epilogue: lane (q,n) holds rows b=B0+4q+r, col c=n, 4 consec s ----
#pragma unroll
    for (int r = 0; r < 4; ++r) {
        const int b = B0 + 4 * q + r;
        float* dst = out + ((size_t)(b * COUT + n)) * SLOC + s0;
        *(floatx4*)dst = floatx4{acc0[r] + bias0 * accc0[r],
                                 acc1[r] + bias1 * accc1[r],
                                 acc2[r] + bias2 * accc2[r],
                                 acc3[r] + bias3 * accc3[r]};
    }
}

extern "C" void kernel_launch(void* const* d_in, const int* in_sizes, int n_in,
                              void* d_out, int out_size, void* d_ws, size_t ws_size,
                              hipStream_t stream) {
    const float* X    = (const float*)d_in[0];   // [64][32][64][64] fp32
    const float* Wg   = (const float*)d_in[1];   // [4096][288][16] fp32
    const float* bias = (const float*)d_in[2];   // [4096] fp32
    float* out = (float*)d_out;                  // [64][16][4096] fp32

    // Workspace: xt only: 66*66*64*32*2 = 17,842,176 B
    unsigned short* xt = (unsigned short*)d_ws;

    prep_kernel<<<2048, 256, 0, stream>>>(X, xt);
    varconv_kernel<<<1024, 256, 0, stream>>>(xt, Wg, bias, out);
}